// Round 2
// baseline (5605.090 us; speedup 1.0000x reference)
//
#include <hip/hip_runtime.h>

#define T_LEN 16384
#define HDIM 64
#define BATCH 64

// K = DELAY / OS_FACTOR = 1 / 1.5 = 2/3
#define KBLEND      (2.0f / 3.0f)
#define ONE_MINUS_K (1.0f / 3.0f)

typedef float v2f __attribute__((ext_vector_type(2)));

__device__ __forceinline__ float tanh_fast(float x) {
    // tanh(x) = sign(x) * (1 - e) / (1 + e),  e = exp(-2|x|)
    float ax = fabsf(x);
    float e  = __expf(-2.0f * ax);
    float t  = (1.0f - e) * __builtin_amdgcn_rcpf(1.0f + e);
    return copysignf(t, x);
}

__global__ __launch_bounds__(HDIM, 1) void rnn_delayline_kernel(
    const float* __restrict__ x,      // [B, T, 1]
    const float* __restrict__ Wih,    // [H, 1]
    const float* __restrict__ Whh,    // [H, H] row-major; y[h] = sum_k Whh[h][k]*hprev[k]
    const float* __restrict__ bih,    // [H]
    const float* __restrict__ bhh,    // [H]
    float* __restrict__ out_states,   // [B, T, H]
    float* __restrict__ out_hlast)    // [B, H]
{
    const int lane = threadIdx.x;   // h index, 0..63 (one wave per block)
    const int b    = blockIdx.x;    // batch index

    __shared__ __align__(16) float hbuf[HDIM];
    __shared__ __align__(16) float xbuf[HDIM];

    // This lane's W_hh row, held in VGPRs as 32 packed float2 (for v_pk_fma_f32).
    v2f w2[32];
    {
        const float4* wrow = reinterpret_cast<const float4*>(Whh + lane * HDIM);
        #pragma unroll
        for (int kk = 0; kk < 16; ++kk) {
            float4 v = wrow[kk];
            w2[2*kk+0] = (v2f){v.x, v.y};
            w2[2*kk+1] = (v2f){v.z, v.w};
        }
    }
    const float wih  = Wih[lane];
    const float bias = bih[lane] + bhh[lane];   // b_ih + b_hh folded

    float h = 0.0f;
    hbuf[lane] = 0.0f;

    const float* xb = x + (size_t)b * T_LEN;
    xbuf[lane] = xb[lane];          // chunk 0 of x (64 timesteps per chunk)
    __syncthreads();                // once, before the sequential loop

    float* outp = out_states + ((size_t)b * T_LEN) * HDIM + lane;

    const int NCHUNK = T_LEN / HDIM;   // 256
    for (int c = 0; c < NCHUNK; ++c) {
        // Prefetch next x chunk early (plenty of latency slack off-chain)
        float xnext = 0.0f;
        if (c + 1 < NCHUNK) xnext = xb[(size_t)(c + 1) * HDIM + lane];

        #pragma unroll 4
        for (int tt = 0; tt < HDIM; ++tt) {
            // Off-critical-path terms: compute while the h broadcast is in flight.
            float xs    = xbuf[tt];               // uniform-address broadcast read
            float xpre  = fmaf(xs, wih, bias);    // x*W_ih + (b_ih+b_hh)
            float hpre  = ONE_MINUS_K * h;        // (1-K)*h, ready before tanh

            // y[lane] = sum_k Whh[lane][k] * h_prev[k]  (packed fp32, 32 pk_fma)
            const float4* hb4 = reinterpret_cast<const float4*>(hbuf);
            v2f acc[8];
            #pragma unroll
            for (int kk = 0; kk < 16; ++kk) {
                float4 hv = hb4[kk];              // ds_read_b128 broadcast
                v2f h0 = (v2f){hv.x, hv.y};
                v2f h1 = (v2f){hv.z, hv.w};
                const int i0 = 2*kk, i1 = 2*kk+1;
                if (kk < 4) {                     // compile-time branch: init accs
                    acc[i0] = w2[i0] * h0;
                    acc[i1] = w2[i1] * h1;
                } else {
                    acc[i0 & 7] = __builtin_elementwise_fma(w2[i0], h0, acc[i0 & 7]);
                    acc[i1 & 7] = __builtin_elementwise_fma(w2[i1], h1, acc[i1 & 7]);
                }
            }
            v2f r0 = acc[0] + acc[1], r1 = acc[2] + acc[3];
            v2f r2 = acc[4] + acc[5], r3 = acc[6] + acc[7];
            v2f s  = (r0 + r1) + (r2 + r3);
            float y = xpre + (s.x + s.y);

            float cell = tanh_fast(y);
            h = fmaf(KBLEND, cell, hpre);         // h = (1-K)h + K*cell

            // Publish for next step. Same-array aliasing orders this write
            // against next iteration's hbuf reads; same-wave LDS is in-order.
            hbuf[lane] = h;

            *outp = h;                            // coalesced 256B/wave store
            outp += HDIM;
        }

        // Rotate x chunk (aliasing with xbuf[tt] reads preserves order)
        xbuf[lane] = xnext;
    }

    out_hlast[b * HDIM + lane] = h;
}

extern "C" void kernel_launch(void* const* d_in, const int* in_sizes, int n_in,
                              void* d_out, int out_size, void* d_ws, size_t ws_size,
                              hipStream_t stream) {
    const float* x   = (const float*)d_in[0];
    const float* Wih = (const float*)d_in[1];
    const float* Whh = (const float*)d_in[2];
    const float* bih = (const float*)d_in[3];
    const float* bhh = (const float*)d_in[4];

    float* out_states = (float*)d_out;
    float* out_hlast  = out_states + (size_t)BATCH * T_LEN * HDIM;

    rnn_delayline_kernel<<<dim3(BATCH), dim3(HDIM), 0, stream>>>(
        x, Wih, Whh, bih, bhh, out_states, out_hlast);
}

// Round 3
// 5584.511 us; speedup vs baseline: 1.0037x; 1.0037x over previous
//
#include <hip/hip_runtime.h>

#define T_LEN 16384
#define HDIM 64
#define BATCH 64

// K = DELAY / OS_FACTOR = 1/1.5 = 2/3
#define KBLEND      (2.0f / 3.0f)
#define ONE_MINUS_K (1.0f / 3.0f)
#define KK          (KBLEND * ONE_MINUS_K)   // K*(1-K), for the g-recurrence

typedef float v2f __attribute__((ext_vector_type(2)));

__device__ __forceinline__ float tanh_fast(float x) {
    // tanh(x) = sign(x) * (1 - e) / (1 + e),  e = exp(-2|x|)
    float ax = fabsf(x);
    float e  = __expf(-2.0f * ax);
    float t  = (1.0f - e) * __builtin_amdgcn_rcpf(1.0f + e);
    return copysignf(t, x);
}

__device__ __forceinline__ float lane_bcast(float v, int lane) {
    return __int_as_float(__builtin_amdgcn_readlane(__float_as_int(v), lane));
}

__global__ __launch_bounds__(HDIM, 1) void rnn_delayline_kernel(
    const float* __restrict__ x,      // [B, T, 1]
    const float* __restrict__ Wih,    // [H, 1]
    const float* __restrict__ Whh,    // [H, H] row-major
    const float* __restrict__ bih,    // [H]
    const float* __restrict__ bhh,    // [H]
    float* __restrict__ out_states,   // [B, T, H]
    float* __restrict__ out_hlast)    // [B, H]
{
    const int lane = threadIdx.x;   // h index, 0..63 (one wave per block)
    const int b    = blockIdx.x;    // batch index

    __shared__ __align__(16) float hbuf[HDIM];   // broadcast buffer for cell

    // This lane's W_hh row in VGPRs as 32 packed float2.
    v2f w2[32];
    {
        const float4* wrow = reinterpret_cast<const float4*>(Whh + lane * HDIM);
        #pragma unroll
        for (int kk = 0; kk < 16; ++kk) {
            float4 v = wrow[kk];
            w2[2*kk+0] = (v2f){v.x, v.y};
            w2[2*kk+1] = (v2f){v.z, v.w};
        }
    }
    // Pin: asm outputs can't be rematerialized -> the 64 floats MUST stay
    // register-resident across the whole time loop (VGPR_Count should jump
    // from 52 to ~120; round 1/2 showed the compiler otherwise re-fetches
    // the row from memory inside the serial chain every step).
    #pragma unroll
    for (int i = 0; i < 32; ++i) asm volatile("" : "+v"(w2[i]));

    const float wih  = Wih[lane];
    const float bias = bih[lane] + bhh[lane];   // b_ih + b_hh folded

    // State:
    //   dot = W·cell of the PREVIOUS step (dot_{t-1})
    //   g   = (1-K)*d_{t-2}, where d_t = W·h_t   (so arg_t = xpre_t + g + K*dot)
    //   h   = h_{t-1} (per-lane), off the critical chain
    float h = 0.0f, dot = 0.0f, g = 0.0f;

    const float* xb = x + (size_t)b * T_LEN;
    float xcur = xb[lane];          // 64 timesteps of x per chunk, one per lane

    float* outp = out_states + ((size_t)b * T_LEN) * HDIM + lane;

    const int NCHUNK = T_LEN / HDIM;   // 256
    for (int c = 0; c < NCHUNK; ++c) {
        float xnext = 0.0f;
        if (c + 1 < NCHUNK) xnext = xb[(size_t)(c + 1) * HDIM + lane];

        #pragma unroll 4
        for (int tt = 0; tt < HDIM; ++tt) {
            // ---- off-chain inputs (ready before dot arrives) ----
            float xt   = lane_bcast(xcur, tt);        // x_t (I=1: same for all h)
            float xpre = fmaf(xt, wih, bias);         // x*W_ih + b_ih + b_hh
            float base = xpre + g;                    // xpre_t + (1-K)*d_{t-2}

            // ---- critical chain ----
            float arg  = fmaf(KBLEND, dot, base);     // + K*dot_{t-1} = xpre + d_{t-1}
            float cell = tanh_fast(arg);
            hbuf[lane] = cell;                        // publish (same-wave, in-order)

            // ---- off-chain state updates (overlap the LDS round-trip) ----
            g = fmaf(ONE_MINUS_K, g, KK * dot);       // g_{t-1} = (1-K)g_{t-2}+K(1-K)dot
            h = fmaf(KBLEND, cell - h, h);            // h_t = h + K*(cell - h)
            *outp = h;                                // coalesced 256B/wave store
            outp += HDIM;

            // ---- matvec: dot_t[lane] = sum_k Whh[lane][k] * cell_k ----
            const float4* hb4 = reinterpret_cast<const float4*>(hbuf);
            v2f acc[8];
            #pragma unroll
            for (int kk = 0; kk < 16; ++kk) {
                float4 hv = hb4[kk];                  // ds_read_b128 broadcast
                v2f h0 = (v2f){hv.x, hv.y};
                v2f h1 = (v2f){hv.z, hv.w};
                const int i0 = 2*kk, i1 = 2*kk+1;
                if (kk < 4) {
                    acc[i0] = w2[i0] * h0;
                    acc[i1] = w2[i1] * h1;
                } else {
                    acc[i0 & 7] = __builtin_elementwise_fma(w2[i0], h0, acc[i0 & 7]);
                    acc[i1 & 7] = __builtin_elementwise_fma(w2[i1], h1, acc[i1 & 7]);
                }
            }
            v2f r0 = acc[0] + acc[1], r1 = acc[2] + acc[3];
            v2f r2 = acc[4] + acc[5], r3 = acc[6] + acc[7];
            v2f s  = (r0 + r1) + (r2 + r3);
            dot = s.x + s.y;                          // dot_t
        }

        xcur = xnext;   // rotate x chunk (register, no LDS)
    }

    out_hlast[b * HDIM + lane] = h;
}

extern "C" void kernel_launch(void* const* d_in, const int* in_sizes, int n_in,
                              void* d_out, int out_size, void* d_ws, size_t ws_size,
                              hipStream_t stream) {
    const float* x   = (const float*)d_in[0];
    const float* Wih = (const float*)d_in[1];
    const float* Whh = (const float*)d_in[2];
    const float* bih = (const float*)d_in[3];
    const float* bhh = (const float*)d_in[4];

    float* out_states = (float*)d_out;
    float* out_hlast  = out_states + (size_t)BATCH * T_LEN * HDIM;

    rnn_delayline_kernel<<<dim3(BATCH), dim3(HDIM), 0, stream>>>(
        x, Wih, Whh, bih, bhh, out_states, out_hlast);
}

// Round 4
// 3112.703 us; speedup vs baseline: 1.8007x; 1.7941x over previous
//
#include <hip/hip_runtime.h>

#define T_LEN 16384
#define HDIM 64
#define BATCH 64

// K = DELAY / OS_FACTOR = 1/1.5 = 2/3
#define KBLEND      (2.0f / 3.0f)
#define ONE_MINUS_K (1.0f / 3.0f)
#define KK          (KBLEND * ONE_MINUS_K)   // K*(1-K), for the g-recurrence

typedef float v2f __attribute__((ext_vector_type(2)));

__device__ __forceinline__ float tanh_fast(float x) {
    // tanh(x) = sign(x) * (1 - e) / (1 + e),  e = exp(-2|x|)
    float ax = fabsf(x);
    float e  = __expf(-2.0f * ax);
    float t  = (1.0f - e) * __builtin_amdgcn_rcpf(1.0f + e);
    return copysignf(t, x);
}

__device__ __forceinline__ float lane_bcast(float v, int lane) {
    return __int_as_float(__builtin_amdgcn_readlane(__float_as_int(v), lane));
}

// waves_per_eu(1,1): make 1 wave/EU the allocator's TARGET (512-VGPR budget),
// not just a lower bound. Rounds 1-3 showed the default heuristic caps at
// ~56 VGPRs and round-trips the 64-float weight row through scratch INSIDE
// the serial dependence chain every timestep.
__global__ __launch_bounds__(HDIM)
__attribute__((amdgpu_waves_per_eu(1, 1)))
void rnn_delayline_kernel(
    const float* __restrict__ x,      // [B, T, 1]
    const float* __restrict__ Wih,    // [H, 1]
    const float* __restrict__ Whh,    // [H, H] row-major
    const float* __restrict__ bih,    // [H]
    const float* __restrict__ bhh,    // [H]
    float* __restrict__ out_states,   // [B, T, H]
    float* __restrict__ out_hlast)    // [B, H]
{
    const int lane = threadIdx.x;   // h index, 0..63 (one wave per block)
    const int b    = blockIdx.x;    // batch index

    __shared__ __align__(16) float hbuf[HDIM];   // broadcast buffer for cell

    // This lane's W_hh row in VGPRs as 32 packed float2.
    v2f w2[32];
    {
        const float4* wrow = reinterpret_cast<const float4*>(Whh + lane * HDIM);
        #pragma unroll
        for (int kk = 0; kk < 16; ++kk) {
            float4 v = wrow[kk];
            w2[2*kk+0] = (v2f){v.x, v.y};
            w2[2*kk+1] = (v2f){v.z, v.w};
        }
    }

    const float wih  = Wih[lane];
    const float bias = bih[lane] + bhh[lane];   // b_ih + b_hh folded

    // State: dot = W·cell_{t-1}; g = (1-K)*d_{t-2} with d_t = W·h_t; h off-chain.
    float h = 0.0f, dot = 0.0f, g = 0.0f;

    const float* xb = x + (size_t)b * T_LEN;
    float xcur = xb[lane];          // 64 timesteps of x per chunk, one per lane

    float* outp = out_states + ((size_t)b * T_LEN) * HDIM + lane;

    const int NCHUNK = T_LEN / HDIM;   // 256
    for (int c = 0; c < NCHUNK; ++c) {
        float xnext = 0.0f;
        if (c + 1 < NCHUNK) xnext = xb[(size_t)(c + 1) * HDIM + lane];

        #pragma unroll 4
        for (int tt = 0; tt < HDIM; ++tt) {
            // In-loop pin: weights become loop-carried asm outputs -> cannot be
            // rematerialized from Whh, and with the 512-VGPR budget the only
            // sane allocation is to keep all 64 floats resident. Empty asm ->
            // zero instructions.
            asm volatile("" : "+v"(w2[0]), "+v"(w2[1]), "+v"(w2[2]), "+v"(w2[3]),
                              "+v"(w2[4]), "+v"(w2[5]), "+v"(w2[6]), "+v"(w2[7]));
            asm volatile("" : "+v"(w2[8]), "+v"(w2[9]), "+v"(w2[10]), "+v"(w2[11]),
                              "+v"(w2[12]), "+v"(w2[13]), "+v"(w2[14]), "+v"(w2[15]));
            asm volatile("" : "+v"(w2[16]), "+v"(w2[17]), "+v"(w2[18]), "+v"(w2[19]),
                              "+v"(w2[20]), "+v"(w2[21]), "+v"(w2[22]), "+v"(w2[23]));
            asm volatile("" : "+v"(w2[24]), "+v"(w2[25]), "+v"(w2[26]), "+v"(w2[27]),
                              "+v"(w2[28]), "+v"(w2[29]), "+v"(w2[30]), "+v"(w2[31]));

            // ---- off-chain inputs (ready before dot arrives) ----
            float xt   = lane_bcast(xcur, tt);        // x_t (I=1: same for all h)
            float xpre = fmaf(xt, wih, bias);         // x*W_ih + b_ih + b_hh
            float base = xpre + g;                    // xpre_t + (1-K)*d_{t-2}

            // ---- critical chain ----
            float arg  = fmaf(KBLEND, dot, base);     // + K*dot_{t-1}
            float cell = tanh_fast(arg);
            hbuf[lane] = cell;                        // publish (same-wave, in-order)

            // ---- off-chain state updates (overlap the LDS round-trip) ----
            g = fmaf(ONE_MINUS_K, g, KK * dot);       // (1-K)g + K(1-K)dot
            h = fmaf(KBLEND, cell - h, h);            // h = h + K*(cell - h)
            *outp = h;                                // coalesced 256B/wave store
            outp += HDIM;

            // ---- matvec: dot_t[lane] = sum_k Whh[lane][k] * cell_k ----
            const float4* hb4 = reinterpret_cast<const float4*>(hbuf);
            v2f acc[8];
            #pragma unroll
            for (int kk = 0; kk < 16; ++kk) {
                float4 hv = hb4[kk];                  // ds_read_b128 broadcast
                v2f h0 = (v2f){hv.x, hv.y};
                v2f h1 = (v2f){hv.z, hv.w};
                const int i0 = 2*kk, i1 = 2*kk+1;
                if (kk < 4) {
                    acc[i0] = w2[i0] * h0;
                    acc[i1] = w2[i1] * h1;
                } else {
                    acc[i0 & 7] = __builtin_elementwise_fma(w2[i0], h0, acc[i0 & 7]);
                    acc[i1 & 7] = __builtin_elementwise_fma(w2[i1], h1, acc[i1 & 7]);
                }
            }
            v2f r0 = acc[0] + acc[1], r1 = acc[2] + acc[3];
            v2f r2 = acc[4] + acc[5], r3 = acc[6] + acc[7];
            v2f s  = (r0 + r1) + (r2 + r3);
            dot = s.x + s.y;                          // dot_t
        }

        xcur = xnext;   // rotate x chunk (register, no LDS)
    }

    out_hlast[b * HDIM + lane] = h;
}

extern "C" void kernel_launch(void* const* d_in, const int* in_sizes, int n_in,
                              void* d_out, int out_size, void* d_ws, size_t ws_size,
                              hipStream_t stream) {
    const float* x   = (const float*)d_in[0];
    const float* Wih = (const float*)d_in[1];
    const float* Whh = (const float*)d_in[2];
    const float* bih = (const float*)d_in[3];
    const float* bhh = (const float*)d_in[4];

    float* out_states = (float*)d_out;
    float* out_hlast  = out_states + (size_t)BATCH * T_LEN * HDIM;

    rnn_delayline_kernel<<<dim3(BATCH), dim3(HDIM), 0, stream>>>(
        x, Wih, Whh, bih, bhh, out_states, out_hlast);
}

// Round 5
// 2675.003 us; speedup vs baseline: 2.0954x; 1.1636x over previous
//
#include <hip/hip_runtime.h>

#define T_LEN 16384
#define HDIM 64
#define BATCH 64

// K = DELAY / OS_FACTOR = 1/1.5 = 2/3
#define KBLEND      (2.0f / 3.0f)
#define ONE_MINUS_K (1.0f / 3.0f)
#define KK          (KBLEND * ONE_MINUS_K)     // K*(1-K), for the g-recurrence

// tanh(x) = 1 - 2/(1 + exp2(C2*x)); C2 = 2*log2(e). Exact algebra, 5-dep chain.
#define C2   2.8853900817779268f
#define C2K  (C2 * KBLEND)                     // folds arg's K*dot fma with the C2 scaling

typedef _Float16 h2 __attribute__((ext_vector_type(2)));

__device__ __forceinline__ float lane_bcast(float v, int lane) {
    return __int_as_float(__builtin_amdgcn_readlane(__float_as_int(v), lane));
}

// waves_per_eu(1,1): 512-VGPR budget so the weight row stays register-resident
// (round 4: 56->132 VGPRs, 5585->3113 us).
__global__ __launch_bounds__(HDIM)
__attribute__((amdgpu_waves_per_eu(1, 1)))
void rnn_delayline_kernel(
    const float* __restrict__ x,      // [B, T, 1]
    const float* __restrict__ Wih,    // [H, 1]
    const float* __restrict__ Whh,    // [H, H] row-major
    const float* __restrict__ bih,    // [H]
    const float* __restrict__ bhh,    // [H]
    float* __restrict__ out_states,   // [B, T, H]
    float* __restrict__ out_hlast)    // [B, H]
{
    const int lane = threadIdx.x;   // h index, 0..63 (one wave per block)
    const int b    = blockIdx.x;    // batch index

    __shared__ __align__(16) _Float16 hbuf[HDIM];   // f16 cell broadcast (128 B)

    // This lane's W_hh row as 32 packed f16 pairs (for v_dot2_f32_f16).
    h2 w2h[32];
    {
        const float4* wrow = reinterpret_cast<const float4*>(Whh + lane * HDIM);
        #pragma unroll
        for (int kk = 0; kk < 16; ++kk) {
            float4 v = wrow[kk];
            w2h[2*kk+0] = (h2){(_Float16)v.x, (_Float16)v.y};
            w2h[2*kk+1] = (h2){(_Float16)v.z, (_Float16)v.w};
        }
    }

    const float wih  = Wih[lane];
    const float bias = bih[lane] + bhh[lane];   // b_ih + b_hh folded

    // State: dot = W·cell_{t-1}; g = (1-K)*d_{t-2} with d_t = W·h_t; h off-chain.
    float h = 0.0f, dot = 0.0f, g = 0.0f;

    const float* xb = x + (size_t)b * T_LEN;
    float xcur = xb[lane];          // 64 timesteps of x per chunk, one per lane

    float* outp = out_states + ((size_t)b * T_LEN) * HDIM + lane;

    const int NCHUNK = T_LEN / HDIM;   // 256
    for (int c = 0; c < NCHUNK; ++c) {
        float xnext = 0.0f;
        if (c + 1 < NCHUNK) xnext = xb[(size_t)(c + 1) * HDIM + lane];

        #pragma unroll 4
        for (int tt = 0; tt < HDIM; ++tt) {
            // In-loop pin: weights are loop-carried asm outputs -> must stay
            // register-resident (zero instructions emitted).
            asm volatile("" : "+v"(w2h[0]), "+v"(w2h[1]), "+v"(w2h[2]), "+v"(w2h[3]),
                              "+v"(w2h[4]), "+v"(w2h[5]), "+v"(w2h[6]), "+v"(w2h[7]));
            asm volatile("" : "+v"(w2h[8]), "+v"(w2h[9]), "+v"(w2h[10]), "+v"(w2h[11]),
                              "+v"(w2h[12]), "+v"(w2h[13]), "+v"(w2h[14]), "+v"(w2h[15]));
            asm volatile("" : "+v"(w2h[16]), "+v"(w2h[17]), "+v"(w2h[18]), "+v"(w2h[19]),
                              "+v"(w2h[20]), "+v"(w2h[21]), "+v"(w2h[22]), "+v"(w2h[23]));
            asm volatile("" : "+v"(w2h[24]), "+v"(w2h[25]), "+v"(w2h[26]), "+v"(w2h[27]),
                              "+v"(w2h[28]), "+v"(w2h[29]), "+v"(w2h[30]), "+v"(w2h[31]));

            // ---- off-chain inputs (ready before dot arrives) ----
            float xt   = lane_bcast(xcur, tt);        // x_t (I=1: same for all h)
            float xpre = fmaf(xt, wih, bias);         // x*W_ih + b_ih + b_hh
            float cb   = C2 * (xpre + g);             // C2*(xpre + (1-K)*d_{t-2})

            // ---- critical chain: fma -> exp2 -> add -> rcp -> fma ----
            float targ = fmaf(C2K, dot, cb);          // C2*(arg)
            float e    = __builtin_amdgcn_exp2f(targ);
            float r    = __builtin_amdgcn_rcpf(1.0f + e);
            float cell = fmaf(-2.0f, r, 1.0f);        // tanh(arg), exact algebra

            hbuf[lane] = (_Float16)cell;              // publish (ds_write_b16, in-order)

            // ---- off-chain state updates (overlap the LDS round-trip) ----
            g = fmaf(ONE_MINUS_K, g, KK * dot);       // (1-K)g + K(1-K)dot
            h = fmaf(KBLEND, cell - h, h);            // h = h + K*(cell - h)
            *outp = h;                                // coalesced 256B/wave store
            outp += HDIM;

            // ---- matvec: dot_t[lane] = sum_k Whh[lane][k] * cell_k ----
            // 8x ds_read_b128 (uniform addr broadcast) + 32x v_dot2_f32_f16.
            const uint4* hb4 = reinterpret_cast<const uint4*>(hbuf);
            float acc[8];
            #pragma unroll
            for (int rr = 0; rr < 8; ++rr) {
                uint4 u = hb4[rr];                    // 8 f16 cells
                h2 p0 = __builtin_bit_cast(h2, u.x);
                h2 p1 = __builtin_bit_cast(h2, u.y);
                h2 p2 = __builtin_bit_cast(h2, u.z);
                h2 p3 = __builtin_bit_cast(h2, u.w);
                const int p = 4 * rr;
                if (rr < 2) {                         // compile-time: init accs
                    acc[(p+0)&7] = __builtin_amdgcn_fdot2(w2h[p+0], p0, 0.0f, false);
                    acc[(p+1)&7] = __builtin_amdgcn_fdot2(w2h[p+1], p1, 0.0f, false);
                    acc[(p+2)&7] = __builtin_amdgcn_fdot2(w2h[p+2], p2, 0.0f, false);
                    acc[(p+3)&7] = __builtin_amdgcn_fdot2(w2h[p+3], p3, 0.0f, false);
                } else {
                    acc[(p+0)&7] = __builtin_amdgcn_fdot2(w2h[p+0], p0, acc[(p+0)&7], false);
                    acc[(p+1)&7] = __builtin_amdgcn_fdot2(w2h[p+1], p1, acc[(p+1)&7], false);
                    acc[(p+2)&7] = __builtin_amdgcn_fdot2(w2h[p+2], p2, acc[(p+2)&7], false);
                    acc[(p+3)&7] = __builtin_amdgcn_fdot2(w2h[p+3], p3, acc[(p+3)&7], false);
                }
            }
            float s01 = acc[0] + acc[1], s23 = acc[2] + acc[3];
            float s45 = acc[4] + acc[5], s67 = acc[6] + acc[7];
            dot = (s01 + s23) + (s45 + s67);          // dot_t
        }

        xcur = xnext;   // rotate x chunk (register, no LDS)
    }

    out_hlast[b * HDIM + lane] = h;
}

extern "C" void kernel_launch(void* const* d_in, const int* in_sizes, int n_in,
                              void* d_out, int out_size, void* d_ws, size_t ws_size,
                              hipStream_t stream) {
    const float* x   = (const float*)d_in[0];
    const float* Wih = (const float*)d_in[1];
    const float* Whh = (const float*)d_in[2];
    const float* bih = (const float*)d_in[3];
    const float* bhh = (const float*)d_in[4];

    float* out_states = (float*)d_out;
    float* out_hlast  = out_states + (size_t)BATCH * T_LEN * HDIM;

    rnn_delayline_kernel<<<dim3(BATCH), dim3(HDIM), 0, stream>>>(
        x, Wih, Whh, bih, bhh, out_states, out_hlast);
}